// Round 5
// baseline (402.011 us; speedup 1.0000x reference)
//
#include <hip/hip_runtime.h>
#include <hip/hip_bf16.h>

// GCN: gcn_norm -> conv1(relu) -> conv2(relu) -> mean-pool -> MLP head.
// R5: bucket radix partition + within-bucket counting sort -> node-sorted CSR
// PADDED to a multiple of 8 records per node (zero-weight self-edges), with
// iteration count packed in row_ptr's high bits. Aggregation = wave-per-node,
// uniform fully-unrolled 8-deep gathers, int4 meta loads. deg summed via
// ds_add_f32 during sort. dinv folded into GEMM epilogue (h' = dinv * X@W).

#define DIMH 64
#define BSH 7                 // 128 nodes per bucket
#define BSZ 128
#define NBUCK_MAX 1024
#define EPB 4096              // edges per partition block (391 blocks)
#define BUCK_SLACK 1032       // per-bucket padded-region slack (>= 7*128 + 8)

// ---- pass 1: global bucket histogram (LDS-staged, int atomics) ----
__global__ __launch_bounds__(512) void k_hist(const int* __restrict__ col,
                                              int* __restrict__ cntB, int E, int nbuck) {
    __shared__ int h[NBUCK_MAX];
    for (int i = threadIdx.x; i < nbuck; i += 512) h[i] = 0;
    __syncthreads();
    int ebeg = blockIdx.x * EPB;
    int eend = min(ebeg + EPB, E);
    for (int e = ebeg + threadIdx.x; e < eend; e += 512)
        atomicAdd(&h[col[e] >> BSH], 1);
    __syncthreads();
    for (int i = threadIdx.x; i < nbuck; i += 512)
        if (h[i]) atomicAdd(&cntB[i], h[i]);
}

// ---- scan bucket counts -> base[nbuck+1], cursor init ----
__global__ __launch_bounds__(1024) void k_scan(const int* __restrict__ cntB,
                                               int* __restrict__ base,
                                               int* __restrict__ cursor, int nbuck, int E) {
    __shared__ int s[1024];
    int tid = threadIdx.x;
    int v = tid < nbuck ? cntB[tid] : 0;
    s[tid] = v;
    __syncthreads();
    for (int o = 1; o < 1024; o <<= 1) {
        int t = tid >= o ? s[tid - o] : 0;
        __syncthreads();
        s[tid] += t;
        __syncthreads();
    }
    if (tid < nbuck) {
        int ex = s[tid] - v;
        base[tid] = ex;
        cursor[tid] = ex;
    }
    if (tid == 0) base[nbuck] = E;
}

// ---- pass 2: scatter edges into bucket-contiguous packed records ----
// record: [63:32]=w fp32 bits, [31:8]=src, [7:0]=c_local
__global__ __launch_bounds__(512) void k_scatter(const int* __restrict__ row,
                                                 const int* __restrict__ col,
                                                 const float* __restrict__ ew,
                                                 int* __restrict__ cursor,
                                                 unsigned long long* __restrict__ part,
                                                 int E, int nbuck) {
    __shared__ int h[NBUCK_MAX];
    __shared__ int h2[NBUCK_MAX];
    __shared__ int st[NBUCK_MAX];
    for (int i = threadIdx.x; i < nbuck; i += 512) { h[i] = 0; h2[i] = 0; }
    __syncthreads();
    int ebeg = blockIdx.x * EPB;
    int eend = min(ebeg + EPB, E);
    for (int e = ebeg + threadIdx.x; e < eend; e += 512)
        atomicAdd(&h[col[e] >> BSH], 1);
    __syncthreads();
    for (int i = threadIdx.x; i < nbuck; i += 512) {
        int c = h[i];
        st[i] = c ? atomicAdd(&cursor[i], c) : 0;
    }
    __syncthreads();
    for (int e = ebeg + threadIdx.x; e < eend; e += 512) {
        int c = col[e];
        int b = c >> BSH;
        int r = atomicAdd(&h2[b], 1);
        unsigned long long rec =
            ((unsigned long long)__float_as_uint(ew[e]) << 32) |
            ((unsigned long long)(unsigned)row[e] << 8) |
            (unsigned)(c & (BSZ - 1));
        part[st[b] + r] = rec;
    }
}

// ---- pass 3: within-bucket counting sort -> padded node-sorted CSR ----
// Padded region for bucket b starts at Pb = round_up8(base[b]) + b*BUCK_SLACK.
// Each node's run padded to multiple of 8 with (src=self, w=0) records.
// row_ptr_packed[node] = (n_iters << 26) | start_offset.  deg via ds_add_f32.
__global__ __launch_bounds__(256) void k_sortB(const unsigned long long* __restrict__ part,
                                               const int* __restrict__ base,
                                               int2* __restrict__ csr,
                                               unsigned* __restrict__ rp,
                                               float* __restrict__ dinv, int N) {
    __shared__ int cnt[BSZ];
    __shared__ int scn[BSZ];   // inclusive scan of padded counts
    __shared__ int cur[BSZ];
    __shared__ float dg[BSZ];
    int b = blockIdx.x;
    int nb0 = b << BSH;
    int nn = min(BSZ, N - nb0);
    int tid = threadIdx.x;
    if (tid < BSZ) { cnt[tid] = 0; dg[tid] = 1.0f; }  // self-loop weight 1
    __syncthreads();
    int ebeg = base[b], eend = base[b + 1];
    for (int e = ebeg + tid; e < eend; e += 256)
        atomicAdd(&cnt[(int)(part[e] & (BSZ - 1))], 1);
    __syncthreads();
    int pc = 0;
    if (tid < BSZ) pc = min((cnt[tid] + 7) & ~7, 504);  // padded count, iters<=63
    if (tid < BSZ) scn[tid] = pc;
    __syncthreads();
    for (int o = 1; o < BSZ; o <<= 1) {
        int t = 0;
        if (tid >= o && tid < BSZ) t = scn[tid - o];
        __syncthreads();
        if (tid >= o && tid < BSZ) scn[tid] += t;
        __syncthreads();
    }
    int Pb = ((ebeg + 7) & ~7) + b * BUCK_SLACK;
    int pofs = 0;
    if (tid < BSZ) {
        pofs = scn[tid] - pc;  // exclusive padded offset within bucket
        cur[tid] = pofs;
        if (tid < nn)
            rp[nb0 + tid] = ((unsigned)(pc >> 3) << 26) | (unsigned)(Pb + pofs);
    }
    __syncthreads();
    // place edges (node-sorted), accumulate weighted degree in LDS
    for (int e = ebeg + tid; e < eend; e += 256) {
        unsigned long long rec = part[e];
        int cl = (int)(rec & (BSZ - 1));
        float w = __uint_as_float((unsigned)(rec >> 32));
        int slot = atomicAdd(&cur[cl], 1);
        csr[Pb + slot] = make_int2((int)((rec >> 8) & 0xFFFFFF), __float_as_int(w));
        atomicAdd(&dg[cl], w);
    }
    __syncthreads();
    // fill padding with zero-weight self-edges (L1-hot at gather time)
    if (tid < nn) {
        int c = min(cnt[tid], pc);
        for (int k = c; k < pc; k++)
            csr[Pb + pofs + k] = make_int2(nb0 + tid, 0);
        dinv[nb0 + tid] = rsqrtf(dg[tid]);
    }
}

// ---- Y[i,:] = dinv[i] * (X[i,:] @ W) ----
template <int K, int H>
__global__ __launch_bounds__(256) void k_gemm_s(const float* __restrict__ X,
                                                const float* __restrict__ W,
                                                const float* __restrict__ dinv,
                                                float* __restrict__ Y, int n) {
    __shared__ float Ws[K * H];
    int tid = threadIdx.x;
    for (int i = tid * 4; i < K * H; i += 256 * 4)
        *(float4*)&Ws[i] = *(const float4*)&W[i];
    __syncthreads();

    constexpr int TPR = H / 16;
    constexpr int RPT = 4;
    int c0 = (tid % TPR) * 16;
    int rg = tid / TPR;
    int row0 = blockIdx.x * ((256 / TPR) * RPT) + rg * RPT;
    if (row0 >= n) return;

    float acc[RPT][16];
#pragma unroll
    for (int r = 0; r < RPT; r++)
#pragma unroll
        for (int j = 0; j < 16; j++) acc[r][j] = 0.f;

    int ridx[RPT];
#pragma unroll
    for (int r = 0; r < RPT; r++) ridx[r] = min(row0 + r, n - 1);

    for (int k = 0; k < K; k += 4) {
        float4 xv[RPT];
#pragma unroll
        for (int r = 0; r < RPT; r++)
            xv[r] = *(const float4*)&X[(size_t)ridx[r] * K + k];
#pragma unroll
        for (int kk = 0; kk < 4; kk++) {
            const float* wp = &Ws[(k + kk) * H + c0];
            float w[16];
#pragma unroll
            for (int j = 0; j < 16; j++) w[j] = wp[j];
#pragma unroll
            for (int r = 0; r < RPT; r++) {
                float xs = (&xv[r].x)[kk];
#pragma unroll
                for (int j = 0; j < 16; j++) acc[r][j] += xs * w[j];
            }
        }
    }
#pragma unroll
    for (int r = 0; r < RPT; r++) {
        if (row0 + r < n) {
            float di = dinv[row0 + r];
            float* yr = Y + (size_t)(row0 + r) * H + c0;
#pragma unroll
            for (int j = 0; j < 16; j += 4) {
                float4 o = {di * acc[r][j], di * acc[r][j + 1],
                            di * acc[r][j + 2], di * acc[r][j + 3]};
                *(float4*)&yr[j] = o;
            }
        }
    }
}

// ---- aggregation: wave-per-node, uniform 8-deep gathers, int4 meta ----
// Hin is h' = dinv*h. out = relu(dinv[c]*(h'[c] + sum w*h'[src]) + bias)
__global__ __launch_bounds__(256) void k_aggN(const float* __restrict__ Hin,
                                              const unsigned* __restrict__ rp,
                                              const int2* __restrict__ csr,
                                              const float* __restrict__ dinv,
                                              const float* __restrict__ bias,
                                              float* __restrict__ Hout, int n) {
    int lane = threadIdx.x & 63;
    int wv = threadIdx.x >> 6;
    int node = blockIdx.x * 4 + wv;
    if (node >= n) return;
    unsigned pk = rp[node];
    int p = (int)(pk & 0x3FFFFFFu);
    int iters = (int)(pk >> 26);
    float acc = Hin[(size_t)node * DIMH + lane];  // self term h'[c]
    for (int it = 0; it < iters; it++, p += 8) {
        int4 m0 = *(const int4*)&csr[p];
        int4 m1 = *(const int4*)&csr[p + 2];
        int4 m2 = *(const int4*)&csr[p + 4];
        int4 m3 = *(const int4*)&csr[p + 6];
        float h0 = Hin[(size_t)m0.x * DIMH + lane];
        float h1 = Hin[(size_t)m0.z * DIMH + lane];
        float h2 = Hin[(size_t)m1.x * DIMH + lane];
        float h3 = Hin[(size_t)m1.z * DIMH + lane];
        float h4 = Hin[(size_t)m2.x * DIMH + lane];
        float h5 = Hin[(size_t)m2.z * DIMH + lane];
        float h6 = Hin[(size_t)m3.x * DIMH + lane];
        float h7 = Hin[(size_t)m3.z * DIMH + lane];
        acc += __int_as_float(m0.y) * h0;
        acc += __int_as_float(m0.w) * h1;
        acc += __int_as_float(m1.y) * h2;
        acc += __int_as_float(m1.w) * h3;
        acc += __int_as_float(m2.y) * h4;
        acc += __int_as_float(m2.w) * h5;
        acc += __int_as_float(m3.y) * h6;
        acc += __int_as_float(m3.w) * h7;
    }
    float v = dinv[node] * acc + bias[lane];
    Hout[(size_t)node * DIMH + lane] = v > 0.f ? v : 0.f;
}

// ---- mean-pool (b sorted): per-wave chunk accumulate, flush on change ----
__global__ __launch_bounds__(256) void k_pool(const float* __restrict__ Hin,
                                              const int* __restrict__ b,
                                              float* __restrict__ sums,
                                              float* __restrict__ cntG, int n) {
    const int CHUNK = 64;
    int lane = threadIdx.x & 63;
    int wave = threadIdx.x >> 6;
    int start = (blockIdx.x * 4 + wave) * CHUNK;
    if (start >= n) return;
    int end = min(start + CHUNK, n);
    float acc = 0.f;
    int g_cur = b[start];
    int cnt_local = 0;
    for (int i = start; i < end; i++) {
        int g = b[i];
        if (g != g_cur) {
            atomicAdd(&sums[g_cur * DIMH + lane], acc);
            if (lane == 0) atomicAdd(&cntG[g_cur], (float)cnt_local);
            acc = 0.f;
            cnt_local = 0;
            g_cur = g;
        }
        acc += Hin[(size_t)i * DIMH + lane];
        cnt_local++;
    }
    atomicAdd(&sums[g_cur * DIMH + lane], acc);
    if (lane == 0) atomicAdd(&cntG[g_cur], (float)cnt_local);
}

// ---- head MLP ----
__global__ __launch_bounds__(64) void k_mlp(const float* __restrict__ sums,
                                            const float* __restrict__ cntG,
                                            const float* __restrict__ Wm1,
                                            const float* __restrict__ bm1,
                                            const float* __restrict__ Wm2,
                                            const float* __restrict__ bm2,
                                            float* __restrict__ out, int G) {
    int g = threadIdx.x;
    if (g >= G) return;
    float c = cntG[g];
    float inv = 1.f / (c > 1.f ? c : 1.f);
    float pooled[DIMH];
#pragma unroll
    for (int k = 0; k < DIMH; k++) pooled[k] = sums[g * DIMH + k] * inv;
    float o = 0.f;
    for (int j = 0; j < 32; j++) {
        float t = bm1[j];
#pragma unroll
        for (int k = 0; k < DIMH; k++) t += pooled[k] * Wm1[k * 32 + j];
        t = t > 0.f ? t : 0.f;
        o += t * Wm2[j];
    }
    out[g] = o + bm2[0];
}

// ============================== launch ==============================

extern "C" void kernel_launch(void* const* d_in, const int* in_sizes, int n_in,
                              void* d_out, int out_size, void* d_ws, size_t ws_size,
                              hipStream_t stream) {
    const float* x   = (const float*)d_in[0];
    const int*   ei  = (const int*)d_in[1];
    const float* ew  = (const float*)d_in[2];
    const int*   bvec= (const int*)d_in[3];
    const float* W1  = (const float*)d_in[4];
    const float* b1  = (const float*)d_in[5];
    const float* W2  = (const float*)d_in[6];
    const float* b2  = (const float*)d_in[7];
    const float* Wm1 = (const float*)d_in[8];
    const float* bm1 = (const float*)d_in[9];
    const float* Wm2 = (const float*)d_in[10];
    const float* bm2 = (const float*)d_in[11];
    float* out = (float*)d_out;

    const int E = in_sizes[2];
    const int N = in_sizes[3];
    const int G = out_size;
    const int* row = ei;
    const int* col = ei + E;
    const int nbuck = (N + BSZ - 1) >> BSH;   // 782 for N=100000

    char* p = (char*)d_ws;
    auto alloc = [&](size_t bytes) {
        void* r = (void*)p;
        p += (bytes + 255) & ~(size_t)255;
        return r;
    };

    unsigned long long* part = (unsigned long long*)alloc((size_t)E * 8);
    int2*  csr    = (int2*)alloc(((size_t)E + (size_t)nbuck * BUCK_SLACK + 16) * 8);
    int*   cntB   = (int*)alloc((size_t)nbuck * 4);
    int*   base   = (int*)alloc((size_t)(nbuck + 1) * 4);
    int*   cursor = (int*)alloc((size_t)nbuck * 4);
    unsigned* rp  = (unsigned*)alloc((size_t)N * 4);
    float* dinv   = (float*)alloc((size_t)N * 4);
    float* hA     = (float*)alloc((size_t)N * DIMH * 4);
    float* hB     = (float*)alloc((size_t)N * DIMH * 4);
    float* sums   = (float*)alloc((size_t)(G * DIMH + G) * 4);
    float* cntG   = sums + G * DIMH;

    hipMemsetAsync(cntB, 0, (size_t)nbuck * 4, stream);
    hipMemsetAsync(sums, 0, (size_t)(G * DIMH + G) * 4, stream);

    const int PB = (E + EPB - 1) / EPB;

    // 1. partition + sort -> padded CSR, packed row_ptr, dinv
    k_hist<<<PB, 512, 0, stream>>>(col, cntB, E, nbuck);
    k_scan<<<1, 1024, 0, stream>>>(cntB, base, cursor, nbuck, E);
    k_scatter<<<PB, 512, 0, stream>>>(row, col, ew, cursor, part, E, nbuck);
    k_sortB<<<nbuck, 256, 0, stream>>>(part, base, csr, rp, dinv, N);

    // 2. conv1
    k_gemm_s<128, DIMH><<<(N + 255) / 256, 256, 0, stream>>>(x, W1, dinv, hA, N);
    k_aggN<<<(N + 3) / 4, 256, 0, stream>>>(hA, rp, csr, dinv, b1, hB, N);

    // 3. conv2
    k_gemm_s<DIMH, DIMH><<<(N + 255) / 256, 256, 0, stream>>>(hB, W2, dinv, hA, N);
    k_aggN<<<(N + 3) / 4, 256, 0, stream>>>(hA, rp, csr, dinv, b2, hB, N);

    // 4. pool + head
    k_pool<<<(N + 255) / 256, 256, 0, stream>>>(hB, bvec, sums, cntG, N);
    k_mlp<<<1, 64, 0, stream>>>(sums, cntG, Wm1, bm1, Wm2, bm2, out, G);
}